// Round 1
// baseline (272.090 us; speedup 1.0000x reference)
//
#include <hip/hip_runtime.h>
#include <math.h>

#define IN_DIM 128
#define OUT_DIM 128
#define SIZE_ (IN_DIM*OUT_DIM)
#define BATCH 1024
#define NG 6      // grid points per row
#define NK 12     // extended knots (K=3 each side)
#define NC 8      // coefs per row (NUM+K)
#define GB 32     // batch elements per block
#define BJ 2      // j rows per block

// One thread owns ONE e = j*128+i (so knots + 30 reciprocals + coefs are
// computed once and amortized over GB batch rows), and loops over GB b's.
// Block = 256 threads = BJ(=2) j-rows x 128 i-lanes.
__global__ __launch_bounds__(256, 4) void kan_fused(
    const float* __restrict__ x,          // (BATCH, IN_DIM)
    const float* __restrict__ grid,       // (SIZE, NG)
    const float* __restrict__ coef,       // (SIZE, NC)
    const float* __restrict__ scale_base, // (SIZE,)
    const float* __restrict__ scale_sp,   // (SIZE,)
    const float* __restrict__ mask,       // (SIZE,)
    float* __restrict__ y_out,            // (BATCH, OUT_DIM)
    float* __restrict__ preacts,          // (BATCH, SIZE)
    float* __restrict__ postacts,         // (BATCH, SIZE)
    float* __restrict__ postspline)       // (BATCH, SIZE)
{
    __shared__ float partial[4][GB];      // per-wave y partial sums

    const int tid  = threadIdx.x;
    const int lane = tid & 63;
    const int wave = tid >> 6;            // 0..3 ; waves 0,1 -> j0, waves 2,3 -> j1
    const int i    = tid & (IN_DIM-1);
    const int jj   = tid >> 7;            // 0..BJ-1
    const int jblk = blockIdx.x & 63;     // 64 j-chunks
    const int bblk = blockIdx.x >> 6;     // 32 b-chunks
    const int j    = jblk * BJ + jj;
    const int b0   = bblk * GB;
    const int e    = j * IN_DIM + i;

    // ---- per-e setup (amortized over GB batch rows) ----
    const float g0 = grid[e*NG+0], g1 = grid[e*NG+1], g2 = grid[e*NG+2],
                g3 = grid[e*NG+3], g4 = grid[e*NG+4], g5 = grid[e*NG+5];
    const float h = (g5 - g0) * 0.2f;     // /(NUM) = /(NG-1)
    float t[NK];
    t[0]=g0-3.f*h; t[1]=g0-2.f*h; t[2]=g0-h;
    t[3]=g0; t[4]=g1; t[5]=g2; t[6]=g3; t[7]=g4; t[8]=g5;
    t[9]=g5+h; t[10]=g5+2.f*h; t[11]=g5+3.f*h;

    float r1[11], r2[10], r3[9];          // reciprocal denominators, exact div (one-time)
    #pragma unroll
    for (int k=0;k<11;++k) r1[k] = 1.0f/(t[k+1]-t[k]);
    #pragma unroll
    for (int k=0;k<10;++k) r2[k] = 1.0f/(t[k+2]-t[k]);
    #pragma unroll
    for (int k=0;k<9;++k)  r3[k] = 1.0f/(t[k+3]-t[k]);

    float cf[NC];
    #pragma unroll
    for (int k=0;k<NC;++k) cf[k] = coef[e*NC+k];

    const float mk  = mask[e];
    const float msb = mk * scale_base[e];
    const float mss = mk * scale_sp[e];

    // ---- batch loop ----
    for (int bb=0; bb<GB; ++bb) {
        const int b   = b0 + bb;
        const float v = x[b*IN_DIM + i];          // coalesced, L1/L2-hot
        const int off = b*SIZE_ + e;              // lane-consecutive -> coalesced stores
        preacts[off] = v;

        const float base = v / (1.0f + __expf(-v));   // silu

        float w[NK];
        #pragma unroll
        for (int k=0;k<NK;++k) w[k] = v - t[k];

        float B0[11];
        #pragma unroll
        for (int k=0;k<11;++k)
            B0[k] = (v >= t[k] && v < t[k+1]) ? 1.0f : 0.0f;

        // level kk: B[t] = (v-t_t)/(t_{t+kk}-t_t)*B[t] + (t_{t+kk+1}-v)/(t_{t+kk+1}-t_{t+1})*B[t+1]
        float B1[10];
        #pragma unroll
        for (int k=0;k<10;++k)
            B1[k] = w[k]*r1[k]*B0[k] - w[k+2]*r1[k+1]*B0[k+1];

        float B2[9];
        #pragma unroll
        for (int k=0;k<9;++k)
            B2[k] = w[k]*r2[k]*B1[k] - w[k+3]*r2[k+1]*B1[k+1];

        float B3[8];
        #pragma unroll
        for (int k=0;k<8;++k)
            B3[k] = w[k]*r3[k]*B2[k] - w[k+4]*r3[k+1]*B2[k+1];

        float spl = 0.f;
        #pragma unroll
        for (int k=0;k<NC;++k) spl = fmaf(cf[k], B3[k], spl);

        const float y = fmaf(msb, base, mss*spl);
        postspline[off] = spl;
        postacts[off]   = y;

        // reduce y over the 64 i's in this wave (all same j)
        float s = y;
        #pragma unroll
        for (int o=32; o>0; o>>=1) s += __shfl_xor(s, o, 64);
        if (lane == 0) partial[wave][bb] = s;     // each wave owns its slot, no race
    }
    __syncthreads();

    // y_out[b, j] = wave0+wave1 (j0) / wave2+wave3 (j1)
    if (tid < 2*GB) {
        const int jj2 = tid >> 5;                 // GB==32
        const int bb  = tid & (GB-1);
        const float s = partial[jj2*2+0][bb] + partial[jj2*2+1][bb];
        y_out[(b0+bb)*OUT_DIM + jblk*BJ + jj2] = s;
    }
}

extern "C" void kernel_launch(void* const* d_in, const int* in_sizes, int n_in,
                              void* d_out, int out_size, void* d_ws, size_t ws_size,
                              hipStream_t stream) {
    const float* x    = (const float*)d_in[0];
    const float* grid = (const float*)d_in[1];
    const float* coef = (const float*)d_in[2];
    const float* sb   = (const float*)d_in[3];
    const float* ss   = (const float*)d_in[4];
    const float* mk   = (const float*)d_in[5];

    float* out        = (float*)d_out;
    float* y_out      = out;                          // 1024*128
    float* preacts    = y_out + BATCH*OUT_DIM;        // 1024*16384
    float* postacts   = preacts + (size_t)BATCH*SIZE_;
    float* postspline = postacts + (size_t)BATCH*SIZE_;

    dim3 gdim(64*32);   // 64 j-chunks x 32 b-chunks
    kan_fused<<<gdim, 256, 0, stream>>>(x, grid, coef, sb, ss, mk,
                                        y_out, preacts, postacts, postspline);
}

// Round 2
// 232.338 us; speedup vs baseline: 1.1711x; 1.1711x over previous
//
#include <hip/hip_runtime.h>
#include <math.h>

#define IN_DIM 128
#define OUT_DIM 128
#define SIZE_ (IN_DIM*OUT_DIM)
#define BATCH 1024
#define NG 6      // grid points per row
#define NC 8      // coefs per row (NUM+K)
#define GB 32     // batch elements per block
#define BJ 2      // j rows per block
#define CSTRIDE 15  // padded coef row stride in LDS words (gcd(15,32)=1 -> spread banks)

// Uniform-knot KAN forward. Knots are t[k] = g0 + (k-3)*h, h=(g5-g0)/5 (exactly how
// extend_grid builds them; interior grid is linspace so fully uniform). For v in
// [t[m], t[m+1]), u = (v-t[m])/h, the only nonzero cubic B-splines are
//   B3[m-3]=(1-u)^3/6, B3[m-2]=(4-6u^2+3u^3)/6, B3[m-1]=(1+3u+3u^2-3u^3)/6, B3[m]=u^3/6
// (verified against the Cox-de Boor recursion). Dynamic index m would push a register
// array to scratch, so each thread keeps its zero-padded coef row in LDS (own row only,
// no barrier needed) and gathers 4 contiguous entries.
// Block = 256 threads = BJ(=2) j-rows x 128 i-lanes; each thread owns one e=j*128+i
// and loops over GB batch rows (amortizes all per-e setup 32x).
__global__ __launch_bounds__(256, 4) void kan_fused(
    const float* __restrict__ x,          // (BATCH, IN_DIM)
    const float* __restrict__ grid,       // (SIZE, NG)
    const float* __restrict__ coef,       // (SIZE, NC)
    const float* __restrict__ scale_base, // (SIZE,)
    const float* __restrict__ scale_sp,   // (SIZE,)
    const float* __restrict__ mask,       // (SIZE,)
    float* __restrict__ y_out,            // (BATCH, OUT_DIM)
    float* __restrict__ preacts,          // (BATCH, SIZE)
    float* __restrict__ postacts,         // (BATCH, SIZE)
    float* __restrict__ postspline)       // (BATCH, SIZE)
{
    __shared__ float cfp[256 * CSTRIDE];  // 15 KB padded coef rows
    __shared__ float partial[4][GB];      // per-wave y partial sums

    const int tid  = threadIdx.x;
    const int lane = tid & 63;
    const int wave = tid >> 6;            // 0..3 ; waves 0,1 -> j0, waves 2,3 -> j1
    const int i    = tid & (IN_DIM-1);
    const int jj   = tid >> 7;            // 0..BJ-1
    const int jblk = blockIdx.x & 63;     // 64 j-chunks
    const int bblk = blockIdx.x >> 6;     // 32 b-chunks
    const int j    = jblk * BJ + jj;
    const int b0   = bblk * GB;
    const int e    = j * IN_DIM + i;

    // ---- per-e setup (once, amortized over GB batch rows) ----
    const float g0 = grid[e*NG + 0];
    const float g5 = grid[e*NG + 5];
    const float h     = (g5 - g0) * 0.2f;   // matches extend_grid's (g[-1]-g[0])/(NG-1)
    const float t0    = g0 - 3.0f * h;      // leftmost extended knot
    const float inv_h = 1.0f / h;

    // zero-padded coef row: index k+3 holds cf[k]; 3 zeros each side kill
    // out-of-range terms at the grid edges (m=0..2 and m=8..10).
    float* myrow = &cfp[tid * CSTRIDE];
    #pragma unroll
    for (int k = 0; k < 3; ++k) { myrow[k] = 0.0f; myrow[11 + k] = 0.0f; }
    const float4* cf4 = (const float4*)(coef + (size_t)e * NC);  // 32B-aligned
    float4 ca = cf4[0], cb = cf4[1];
    myrow[3] = ca.x; myrow[4] = ca.y; myrow[5]  = ca.z; myrow[6]  = ca.w;
    myrow[7] = cb.x; myrow[8] = cb.y; myrow[9]  = cb.z; myrow[10] = cb.w;

    const float mk  = mask[e];
    const float msb = mk * scale_base[e];
    const float mss = mk * scale_sp[e];
    const float c6  = 0.16666667f;

    // ---- batch loop ----
    for (int bb = 0; bb < GB; ++bb) {
        const int b   = b0 + bb;
        const float v = x[b*IN_DIM + i];          // coalesced, L2-hot (reused by all j)
        const int off = b*SIZE_ + e;              // lane-consecutive -> coalesced stores
        preacts[off] = v;

        const float base = __fdividef(v, 1.0f + __expf(-v));   // silu

        // locate interval: s = (v - t[0])/h ; valid iff s in [0, 11)
        const float s  = (v - t0) * inv_h;
        const bool  ok = (s >= 0.0f) && (s < 11.0f);
        int m = (int)s;
        m = (m < 0) ? 0 : ((m > 10) ? 10 : m);
        const float u  = s - (float)m;

        const float u2 = u * u, u3 = u2 * u;
        const float om = 1.0f - u;
        const float N0 = om * om * om * c6;
        const float N1 = fmaf(3.0f, u3, fmaf(-6.0f, u2, 4.0f)) * c6;
        const float N2 = fmaf(-3.0f, u3, fmaf(3.0f, u2, fmaf(3.0f, u, 1.0f))) * c6;
        const float N3 = u3 * c6;

        // gather 4 contiguous padded coefs: cf[m-3..m] at padded idx m..m+3
        const float cc0 = myrow[m];
        const float cc1 = myrow[m + 1];
        const float cc2 = myrow[m + 2];
        const float cc3 = myrow[m + 3];

        float spl = fmaf(N0, cc0, fmaf(N1, cc1, fmaf(N2, cc2, N3 * cc3)));
        spl = ok ? spl : 0.0f;

        const float y = fmaf(msb, base, mss * spl);
        postspline[off] = spl;
        postacts[off]   = y;

        // reduce y over the 64 i's in this wave (all same j)
        float r = y;
        #pragma unroll
        for (int o = 32; o > 0; o >>= 1) r += __shfl_xor(r, o, 64);
        if (lane == 0) partial[wave][bb] = r;     // each wave owns its slot
    }
    __syncthreads();

    // y_out[b, j] : combine the two waves of each j row
    if (tid < 2*GB) {
        const int jj2 = tid >> 5;                 // GB==32
        const int bb  = tid & (GB-1);
        const float r = partial[jj2*2 + 0][bb] + partial[jj2*2 + 1][bb];
        y_out[(b0 + bb)*OUT_DIM + jblk*BJ + jj2] = r;
    }
}

extern "C" void kernel_launch(void* const* d_in, const int* in_sizes, int n_in,
                              void* d_out, int out_size, void* d_ws, size_t ws_size,
                              hipStream_t stream) {
    const float* x    = (const float*)d_in[0];
    const float* grid = (const float*)d_in[1];
    const float* coef = (const float*)d_in[2];
    const float* sb   = (const float*)d_in[3];
    const float* ss   = (const float*)d_in[4];
    const float* mk   = (const float*)d_in[5];

    float* out        = (float*)d_out;
    float* y_out      = out;                          // 1024*128
    float* preacts    = y_out + BATCH*OUT_DIM;        // 1024*16384
    float* postacts   = preacts + (size_t)BATCH*SIZE_;
    float* postspline = postacts + (size_t)BATCH*SIZE_;

    dim3 gdim(64*32);   // 64 j-chunks x 32 b-chunks
    kan_fused<<<gdim, 256, 0, stream>>>(x, grid, coef, sb, ss, mk,
                                        y_out, preacts, postacts, postspline);
}